// Round 10
// baseline (3275.791 us; speedup 1.0000x reference)
//
#include <hip/hip_runtime.h>
#include <cstdint>
#include <cstddef>

// Problem dims (fixed)
#define BB 2048
#define SS 256
#define HH 256
#define AA 2
#define TT 50
// Pipeline: 3 layer-groups x 32 blocks, 64 rows/block, 512 thr (8 waves), 1 blk/CU
#define ROWS  64
#define NTHR  512
#define NLG   32
#define NGRID 96
#define K4PAD 1088           // floats per k4 tile: 8hh*32h0*4k = 1024 + 64 pad
#define WLAYER (64 * K4PAD)
#define LSTR  68             // in_lds row stride (floats): 64 j + 4 pad, 272B (16B-mult)
#define S3P   258            // s3_lds row stride

struct Params {
  const float* x;
  const float* fu[3]; const float* fv[3]; const float* fs[3];
  const float* f4u; const float* f4v; const float* f4s;
  const float* W[3]; const float* bs[3];
  const float* W4; const float* b4;
  float* out;
  float* wt3;        // [3][64 k4][8 hh][32 h0][4 k] padded
  float* partials;   // [4 ch][2 par][6 st][32 g]
  unsigned* flags;   // [0..63] prod[hop][g], [64..127] ack[hop][g],
                     // [256..258] stats_ctr[L], [260] init_ctr
  float* sbuf;       // [2 hop][2 par][2048][256] spikes
  float* xT;         // [TT][BB*SS] transposed input (optional)
  int use_xt;
};

__device__ __forceinline__ void pstore(float* p, float v) {
  __hip_atomic_store(p, v, __ATOMIC_RELAXED, __HIP_MEMORY_SCOPE_AGENT);
}
__device__ __forceinline__ float pload(const float* p) {
  return __hip_atomic_load(p, __ATOMIC_RELAXED, __HIP_MEMORY_SCOPE_AGENT);
}
__device__ __forceinline__ unsigned uload_acq(const unsigned* p) {
  return __hip_atomic_load(p, __ATOMIC_ACQUIRE, __HIP_MEMORY_SCOPE_AGENT);
}
__device__ __forceinline__ void ustore_rel(unsigned* p, unsigned v) {
  __hip_atomic_store(p, v, __ATOMIC_RELEASE, __HIP_MEMORY_SCOPE_AGENT);
}
__device__ __forceinline__ void uadd(unsigned* p) {
  __hip_atomic_fetch_add(p, 1u, __ATOMIC_ACQ_REL, __HIP_MEMORY_SCOPE_AGENT);
}

__global__ __launch_bounds__(NTHR, 2)
void snn_pipe(Params p) {
#pragma clang fp contract(off)
  const int tid = threadIdx.x;
  const int blk = blockIdx.x;
  const int L   = blk >> 5;          // 0,1,2  (group 2 also does layer 4)
  const int g   = blk & 31;          // row-block within group
  const int B0  = g * ROWS;

  const int h0  = tid & 31;          // thread covers h0 + 32*hh, hh=0..7
  const int jg  = tid >> 5;          // 0..15
  const int j0  = jg << 2;           // 4 batch rows per thread
  const int sid = tid & 255;         // staging: s/h index
  const int jq  = tid >> 8;          // 0..1 staging row half

  __shared__ __align__(16) float in_lds[HH * LSTR];   // [k][j(64)+pad]
  __shared__ __align__(16) float s3_lds[ROWS * S3P];  // L2: s3 [j][h]
  __shared__ float wred[8][6];
  __shared__ float scal[2][2];       // [0]=own layer, [1]=layer4 (L==2)
  __shared__ float l4u[128], l4v[128], l4s[128], l4t[128],
                   l4acc[128], l4vn[128], l4vth[128];

  // ---- prologue 1: W -> [k4][hh][h0][4] coalesced tiles ----
  {
    const int gtid = blk * NTHR + tid;
    if (gtid < 16384) {
      const int h = gtid & 255, k4 = gtid >> 8;
      const int hh = h >> 5, hl = h & 31;
      #pragma unroll
      for (int l = 0; l < 3; ++l) {
        float4 w = *reinterpret_cast<const float4*>(p.W[l] + (size_t)h * 256 + k4 * 4);
        *reinterpret_cast<float4*>(
            p.wt3 + (size_t)l * WLAYER + (size_t)k4 * K4PAD + hh * 128 + hl * 4) = w;
      }
    }
    // ---- prologue 2: transpose x -> xT[t][b*SS+s] ----
    if (p.use_xt) {
      for (int sid0 = gtid; sid0 < BB * SS; sid0 += NGRID * NTHR) {
        const float* src = p.x + (size_t)sid0 * TT;
        #pragma unroll 1
        for (int t = 0; t < TT; ++t)
          p.xT[(size_t)t * (BB * SS) + sid0] = src[t];
      }
    }
  }

  // ---- per-thread state: 8 h x 4 j cells; s packed as bitmask (s in {0,1}) ----
  float u[8][4], v[8][4], tp[8][4];
  unsigned smask = 0;
  #pragma unroll
  for (int hh = 0; hh < 8; ++hh)
    #pragma unroll
    for (int jj = 0; jj < 4; ++jj) {
      size_t idx = (size_t)(B0 + j0 + jj) * HH + h0 + 32 * hh;
      u[hh][jj] = p.fu[L][idx];
      v[hh][jj] = p.fv[L][idx];
      if (p.fs[L][idx] != 0.0f) smask |= 1u << (hh * 4 + jj);
      tp[hh][jj] = 0.5f;
    }
  float bL[8];
  #pragma unroll
  for (int hh = 0; hh < 8; ++hh) bL[hh] = p.bs[L][h0 + 32 * hh];
  if (L == 2 && tid < 128) {
    size_t idx = (size_t)(B0 + (tid >> 1)) * AA + (tid & 1);
    l4u[tid] = p.f4u[idx]; l4v[tid] = p.f4v[idx]; l4s[tid] = p.f4s[idx];
    l4t[tid] = 0.5f; l4acc[tid] = 0.0f;
  }
  __syncthreads();

  // ---- one-time global init barrier (wt3 + xT visible) ----
  if (tid == 0) {
    uadd(&p.flags[260]);
    while (uload_acq(&p.flags[260]) < (unsigned)NGRID) __builtin_amdgcn_s_sleep(2);
  }
  __syncthreads();

  const float* wbase = p.wt3 + (size_t)L * WLAYER + (h0 << 2);
  float* sb_in  = (L > 0) ? p.sbuf + (size_t)(L - 1) * 2 * BB * HH : nullptr;
  float* sb_out = (L < 2) ? p.sbuf + (size_t)L * 2 * BB * HH : nullptr;

  #pragma unroll 1
  for (int t = 0; t < TT; ++t) {
    // ---- 1. stage input [k][j] into in_lds ----
    if (L == 0) {
      if (p.use_xt) {
        const float* base = p.xT + (size_t)t * (BB * SS) + (size_t)B0 * SS;
        #pragma unroll
        for (int iq = 0; iq < 8; ++iq) {
          const int j = jq * 32 + iq * 4;
          float4 vv = make_float4(base[(size_t)(j + 0) * SS + sid],
                                  base[(size_t)(j + 1) * SS + sid],
                                  base[(size_t)(j + 2) * SS + sid],
                                  base[(size_t)(j + 3) * SS + sid]);
          *reinterpret_cast<float4*>(&in_lds[sid * LSTR + j]) = vv;
        }
      } else {
        #pragma unroll
        for (int iq = 0; iq < 8; ++iq) {
          const int j = jq * 32 + iq * 4;
          float4 vv = make_float4(
              p.x[((size_t)(B0 + j + 0) * SS + sid) * TT + t],
              p.x[((size_t)(B0 + j + 1) * SS + sid) * TT + t],
              p.x[((size_t)(B0 + j + 2) * SS + sid) * TT + t],
              p.x[((size_t)(B0 + j + 3) * SS + sid) * TT + t]);
          *reinterpret_cast<float4*>(&in_lds[sid * LSTR + j]) = vv;
        }
      }
    } else {
      const int hop = L - 1;
      if (tid == 0) {
        while (uload_acq(&p.flags[hop * 32 + g]) < (unsigned)(t + 1))
          __builtin_amdgcn_s_sleep(2);
      }
      __syncthreads();
      const float* src = sb_in + (size_t)(t & 1) * BB * HH;
      #pragma unroll
      for (int iq = 0; iq < 8; ++iq) {
        const int j = jq * 32 + iq * 4;
        float4 vv = make_float4(pload(src + (size_t)(B0 + j + 0) * HH + sid),
                                pload(src + (size_t)(B0 + j + 1) * HH + sid),
                                pload(src + (size_t)(B0 + j + 2) * HH + sid),
                                pload(src + (size_t)(B0 + j + 3) * HH + sid));
        *reinterpret_cast<float4*>(&in_lds[sid * LSTR + j]) = vv;
      }
      __syncthreads();   // staging reads done
      if (tid == 0) ustore_rel(&p.flags[64 + hop * 32 + g], (unsigned)(t + 1));
    }
    __syncthreads();     // in_lds ready

    // ---- 2. GEMM: acc[hh][jj] += W[h][k]*in[k][j], ascending k (bit-exact) ----
    float acc[8][4];
    #pragma unroll
    for (int hh = 0; hh < 8; ++hh)
      #pragma unroll
      for (int jj = 0; jj < 4; ++jj) acc[hh][jj] = 0.0f;
    #pragma unroll 1
    for (int k4 = 0; k4 < 64; ++k4) {
      const float* wt = wbase + (size_t)k4 * K4PAD;
      float4 wv[8];
      #pragma unroll
      for (int hh = 0; hh < 8; ++hh)
        wv[hh] = *reinterpret_cast<const float4*>(wt + hh * 128);
      #pragma unroll
      for (int q = 0; q < 4; ++q) {
        const int k = k4 * 4 + q;
        float4 iv = *reinterpret_cast<const float4*>(&in_lds[k * LSTR + j0]);
        #pragma unroll
        for (int hh = 0; hh < 8; ++hh) {
          const float w = (q == 0) ? wv[hh].x : (q == 1) ? wv[hh].y
                        : (q == 2) ? wv[hh].z : wv[hh].w;
          acc[hh][0] = fmaf(iv.x, w, acc[hh][0]);
          acc[hh][1] = fmaf(iv.y, w, acc[hh][1]);
          acc[hh][2] = fmaf(iv.z, w, acc[hh][2]);
          acc[hh][3] = fmaf(iv.w, w, acc[hh][3]);
        }
      }
    }

    // ---- 3. stats(t-1): group sync, cross-block reduce, temporal update ----
    if (t > 0) {
      if (tid == 0) {
        while (uload_acq(&p.flags[256 + L]) < 32u * (unsigned)t)
          __builtin_amdgcn_s_sleep(2);
      }
      __syncthreads();
      {
        const int wv = tid >> 6, ln = tid & 63;
        if ((wv == 0 || (wv == 1 && L == 2)) && ln < 32) {
          const int ch = (wv == 0) ? L : 3;
          const float* pb = p.partials + (size_t)(ch * 2 + ((t - 1) & 1)) * 6 * 32;
          float r[6];
          #pragma unroll
          for (int st = 0; st < 6; ++st) {
            float rr = pload(pb + st * 32 + ln);
            if (st == 0 || st == 3) {
              #pragma unroll
              for (int m = 1; m < 32; m <<= 1) rr += __shfl_xor(rr, m);
            } else if (st == 1 || st == 4) {
              #pragma unroll
              for (int m = 1; m < 32; m <<= 1) rr = fmaxf(rr, __shfl_xor(rr, m));
            } else {
              #pragma unroll
              for (int m = 1; m < 32; m <<= 1) rr = fminf(rr, __shfl_xor(rr, m));
            }
            r[st] = rr;
          }
          if (ln == 0) {
            const float invN = (ch == 3) ? (1.0f / 4096.0f) : (1.0f / 524288.0f);
            scal[wv][0] = (r[0] * invN) - 0.2f * (r[1] - r[2]);
            scal[wv][1] = (r[3] * invN) - 0.2f * (r[4] - r[5]);
          }
        }
      }
      __syncthreads();
      {
        const float Vm = scal[0][0], Vt = scal[0][1];
        #pragma unroll
        for (int hh = 0; hh < 8; ++hh)
          #pragma unroll
          for (int jj = 0; jj < 4; ++jj) {
            float d = v[hh][jj] - Vm;           // v holds v(t-1)
            float sp = logf(1.0f + expf(d * 0.25f));
            tp[hh][jj] = (0.01f * d + Vt) + sp;
          }
      }
      if (L == 2 && tid < 128) {
        const float Vm = scal[1][0], Vt = scal[1][1];
        float d = l4v[tid] - Vm;
        float sp = logf(1.0f + expf(d * 0.25f));
        l4t[tid] = (0.01f * d + Vt) + sp;
      }
      __syncthreads();
    }

    // ---- 4. LIF + per-thread/wave stats ----
    float sv = 0.f, svt = 0.f;
    float mxv = -3.402823466e38f, mnv = 3.402823466e38f;
    float mxvt = -3.402823466e38f, mnvt = 3.402823466e38f;
    unsigned nsmask = 0;
    #pragma unroll
    for (int hh = 0; hh < 8; ++hh) {
      const float bbx = bL[hh];
      #pragma unroll
      for (int jj = 0; jj < 4; ++jj) {
        float un = fmaf(u[hh][jj], 0.5f, acc[hh][jj]) + bbx;
        float vp = v[hh][jj];
        float vd = ((smask >> (hh * 4 + jj)) & 1u) ? 0.0f : vp * 0.75f;
        float vn = vd + un;
        float en = expf((vp - vn) / 3.0f) - 1.0f;
        float vt = 0.5f * tp[hh][jj] + 0.5f * en;
        const bool sx = vn > vt;
        u[hh][jj] = un; v[hh][jj] = vn;
        if (sx) nsmask |= 1u << (hh * 4 + jj);
        sv += vn; svt += vt;
        mxv = fmaxf(mxv, vn); mnv = fminf(mnv, vn);
        mxvt = fmaxf(mxvt, vt); mnvt = fminf(mnvt, vt);
      }
    }
    smask = nsmask;
    #pragma unroll
    for (int m = 1; m < 64; m <<= 1) {
      sv += __shfl_xor(sv, m);   svt += __shfl_xor(svt, m);
      mxv = fmaxf(mxv, __shfl_xor(mxv, m));  mnv = fminf(mnv, __shfl_xor(mnv, m));
      mxvt = fmaxf(mxvt, __shfl_xor(mxvt, m)); mnvt = fminf(mnvt, __shfl_xor(mnvt, m));
    }
    if ((tid & 63) == 0) {
      int wv = tid >> 6;
      wred[wv][0] = sv;  wred[wv][1] = mxv;  wred[wv][2] = mnv;
      wred[wv][3] = svt; wred[wv][4] = mxvt; wred[wv][5] = mnvt;
    }

    // ---- 5. publish spikes ----
    if (L < 2) {
      if (t >= 2 && tid == 0) {
        while (uload_acq(&p.flags[64 + L * 32 + g]) < (unsigned)(t - 1))
          __builtin_amdgcn_s_sleep(2);
      }
      __syncthreads();   // ack ok + wred visible + GEMM in_lds reads done
      float* dst = sb_out + (size_t)(t & 1) * BB * HH;
      #pragma unroll
      for (int hh = 0; hh < 8; ++hh)
        #pragma unroll
        for (int jj = 0; jj < 4; ++jj)
          pstore(dst + (size_t)(B0 + j0 + jj) * HH + h0 + 32 * hh,
                 ((nsmask >> (hh * 4 + jj)) & 1u) ? 1.0f : 0.0f);
      __syncthreads();   // stores drained
      if (tid == 0) ustore_rel(&p.flags[L * 32 + g], (unsigned)(t + 1));
    } else {
      __syncthreads();   // wred visible
      #pragma unroll
      for (int hh = 0; hh < 8; ++hh)
        #pragma unroll
        for (int jj = 0; jj < 4; ++jj)
          s3_lds[(j0 + jj) * S3P + h0 + 32 * hh] =
              ((nsmask >> (hh * 4 + jj)) & 1u) ? 1.0f : 0.0f;
      __syncthreads();   // s3 ready
    }

    // ---- 6. block stats partial -> global ----
    if (tid < 6) {
      const int st = tid;
      float r = wred[0][st];
      if (st == 0 || st == 3) {
        #pragma unroll
        for (int wv = 1; wv < 8; ++wv) r = r + wred[wv][st];
      } else if (st == 1 || st == 4) {
        #pragma unroll
        for (int wv = 1; wv < 8; ++wv) r = fmaxf(r, wred[wv][st]);
      } else {
        #pragma unroll
        for (int wv = 1; wv < 8; ++wv) r = fminf(r, wred[wv][st]);
      }
      pstore(p.partials + (size_t)(L * 2 + (t & 1)) * 6 * 32 + st * 32 + g, r);
    }

    // ---- 7. layer 4 (L2 group only): 128 outs x 4 lanes ----
    if (L == 2) {
      const int d = tid >> 2, c = tid & 3;     // d<128
      const int j4 = d >> 1, a4 = d & 1;
      float part = 0.0f;
      #pragma unroll
      for (int i = 0; i < 64; ++i) {
        int k = c + 4 * i;
        part = fmaf(s3_lds[j4 * S3P + k], p.W4[a4 * HH + k], part);
      }
      #pragma unroll
      for (int m = 1; m < 4; m <<= 1) part += __shfl_xor(part, m);
      if (c == 0) {
        float un = fmaf(l4u[d], 0.5f, part) + p.b4[a4];
        float vp = l4v[d];
        float vd = (vp * 0.75f) * (1.0f - l4s[d]);
        float vn = vd + un;
        float en = expf((vp - vn) / 3.0f) - 1.0f;
        float vt = 0.5f * l4t[d] + 0.5f * en;
        float sx = (vn > vt) ? 1.0f : 0.0f;
        l4u[d] = un; l4v[d] = vn; l4s[d] = sx;
        l4acc[d] += sx; l4vn[d] = vn; l4vth[d] = vt;
      }
      __syncthreads();
      if (tid == 0) {
        float sv4 = l4vn[0], mx4 = l4vn[0], mn4 = l4vn[0];
        float st4 = l4vth[0], mxt4 = l4vth[0], mnt4 = l4vth[0];
        #pragma unroll 1
        for (int d2 = 1; d2 < 128; ++d2) {
          sv4 += l4vn[d2]; mx4 = fmaxf(mx4, l4vn[d2]); mn4 = fminf(mn4, l4vn[d2]);
          st4 += l4vth[d2]; mxt4 = fmaxf(mxt4, l4vth[d2]); mnt4 = fminf(mnt4, l4vth[d2]);
        }
        float* pp = p.partials + (size_t)(3 * 2 + (t & 1)) * 6 * 32 + g;
        pstore(pp + 0 * 32, sv4);  pstore(pp + 1 * 32, mx4);  pstore(pp + 2 * 32, mn4);
        pstore(pp + 3 * 32, st4);  pstore(pp + 4 * 32, mxt4); pstore(pp + 5 * 32, mnt4);
      }
    }

    // ---- 8. arrive group stats counter ----
    __syncthreads();
    if (tid == 0) uadd(&p.flags[256 + L]);
  }

  if (L == 2 && tid < 128)
    p.out[(size_t)(B0 + (tid >> 1)) * AA + (tid & 1)] = l4acc[tid] / 50.0f;
}

extern "C" void kernel_launch(void* const* d_in, const int* in_sizes, int n_in,
                              void* d_out, int out_size, void* d_ws, size_t ws_size,
                              hipStream_t stream) {
  Params p;
  p.x     = (const float*)d_in[0];
  p.fu[0] = (const float*)d_in[1];  p.fv[0] = (const float*)d_in[2];  p.fs[0] = (const float*)d_in[3];
  p.fu[1] = (const float*)d_in[4];  p.fv[1] = (const float*)d_in[5];  p.fs[1] = (const float*)d_in[6];
  p.fu[2] = (const float*)d_in[7];  p.fv[2] = (const float*)d_in[8];  p.fs[2] = (const float*)d_in[9];
  p.f4u   = (const float*)d_in[10]; p.f4v   = (const float*)d_in[11]; p.f4s   = (const float*)d_in[12];
  p.W[0]  = (const float*)d_in[13]; p.bs[0] = (const float*)d_in[14];
  p.W[1]  = (const float*)d_in[15]; p.bs[1] = (const float*)d_in[16];
  p.W[2]  = (const float*)d_in[17]; p.bs[2] = (const float*)d_in[18];
  p.W4    = (const float*)d_in[19]; p.b4    = (const float*)d_in[20];
  p.out   = (float*)d_out;

  float* ws   = (float*)d_ws;
  p.wt3       = ws;                          // 3*69632 = 208896 floats
  p.partials  = ws + 208896;                 // 4*2*6*32 = 1536
  p.flags     = (unsigned*)(ws + 210432);    // 1024 uints
  p.sbuf      = ws + 211456;                 // 2*2*2048*256 = 2,097,152
  p.xT        = ws + 2308608;                // 50*524288 = 26,214,400
  size_t need = ((size_t)2308608 + (size_t)TT * BB * SS) * sizeof(float);
  p.use_xt    = (ws_size >= need) ? 1 : 0;

  hipMemsetAsync((void*)p.flags, 0, 4096, stream);
  snn_pipe<<<dim3(NGRID), dim3(NTHR), 0, stream>>>(p);
}

// Round 11
// 1826.067 us; speedup vs baseline: 1.7939x; 1.7939x over previous
//
#include <hip/hip_runtime.h>
#include <cstdint>
#include <cstddef>

// Problem dims (fixed)
#define BB 2048
#define SS 256
#define HH 256
#define AA 2
#define TT 50
// Pipeline: 3 layer-groups x 64 blocks, 32 rows/block, 512 thr (8 waves)
#define ROWS  32
#define NTHR  512
#define NLG   64
#define NGRID 192
#define K4PAD 1088           // floats per k4 tile: 4hh*64h0*4k = 1024 + 64 pad
#define WLAYER (64 * K4PAD)
#define LSTR  36             // in_lds row stride: 32 j + 4 pad
#define S3P   258            // s3_lds row stride

struct Params {
  const float* x;
  const float* fu[3]; const float* fv[3]; const float* fs[3];
  const float* f4u; const float* f4v; const float* f4s;
  const float* W[3]; const float* bs[3];
  const float* W4; const float* b4;
  float* out;
  float* wt3;        // [3][64 k4][4 hh][64 h0][4 k] padded
  float* partials;   // [4 ch][2 par][6 st][64 g]
  unsigned* flags;   // [0..127] prod[hop][g], [128..255] ack[hop][g],
                     // [256..258] stats_ctr[L], [260] init_ctr
  float* sbuf;       // [2 hop][2 par][2048][256] spikes
  float* xT;         // [TT][BB*SS] transposed input (optional)
  int use_xt;
};

__device__ __forceinline__ void pstore(float* p, float v) {
  __hip_atomic_store(p, v, __ATOMIC_RELAXED, __HIP_MEMORY_SCOPE_AGENT);
}
__device__ __forceinline__ float pload(const float* p) {
  return __hip_atomic_load(p, __ATOMIC_RELAXED, __HIP_MEMORY_SCOPE_AGENT);
}
__device__ __forceinline__ unsigned uload_acq(const unsigned* p) {
  return __hip_atomic_load(p, __ATOMIC_ACQUIRE, __HIP_MEMORY_SCOPE_AGENT);
}
__device__ __forceinline__ void ustore_rel(unsigned* p, unsigned v) {
  __hip_atomic_store(p, v, __ATOMIC_RELEASE, __HIP_MEMORY_SCOPE_AGENT);
}
__device__ __forceinline__ void uadd(unsigned* p) {
  __hip_atomic_fetch_add(p, 1u, __ATOMIC_ACQ_REL, __HIP_MEMORY_SCOPE_AGENT);
}

__global__ __launch_bounds__(NTHR, 2)
void snn_pipe(Params p) {
#pragma clang fp contract(off)
  const int tid = threadIdx.x;
  const int blk = blockIdx.x;
  const int L   = blk >> 6;          // 0,1,2  (group 2 also does layer 4)
  const int g   = blk & 63;          // row-block within group
  const int B0  = g * ROWS;

  const int h0  = tid & 63;          // thread covers h0 + 64*hh, hh=0..3
  const int jg  = tid >> 6;          // 0..7
  const int j0  = jg << 2;           // 4 batch rows per thread
  const int sid = tid & 255;         // staging: s/h index
  const int jq  = tid >> 8;          // 0..1 staging row half

  __shared__ __align__(16) float in_lds[HH * LSTR];   // [k][j(32)+pad]
  __shared__ __align__(16) float s3_lds[ROWS * S3P];  // L2: s3 [j][h]
  __shared__ float wred[8][6];
  __shared__ float scal[2][2];       // [0]=own layer, [1]=layer4 (L==2)
  __shared__ float l4u[64], l4v[64], l4s[64], l4t[64],
                   l4acc[64], l4vn[64], l4vth[64];

  // ---- prologue 1: W -> [k4][hh][h0][4] coalesced tiles ----
  {
    const int gtid = blk * NTHR + tid;
    if (gtid < 16384) {
      const int h = gtid & 255, k4 = gtid >> 8;
      const int hh = h >> 6, hl = h & 63;
      #pragma unroll
      for (int l = 0; l < 3; ++l) {
        float4 w = *reinterpret_cast<const float4*>(p.W[l] + (size_t)h * 256 + k4 * 4);
        *reinterpret_cast<float4*>(
            p.wt3 + (size_t)l * WLAYER + (size_t)k4 * K4PAD + hh * 256 + hl * 4) = w;
      }
    }
    // ---- prologue 2: transpose x -> xT[t][b*SS+s] ----
    if (p.use_xt) {
      for (int sid0 = gtid; sid0 < BB * SS; sid0 += NGRID * NTHR) {
        const float* src = p.x + (size_t)sid0 * TT;
        #pragma unroll 1
        for (int t = 0; t < TT; ++t)
          p.xT[(size_t)t * (BB * SS) + sid0] = src[t];
      }
    }
  }

  // ---- per-thread state: 4 h x 4 j cells; s packed as bitmask ----
  float u[4][4], v[4][4], tp[4][4];
  unsigned smask = 0;
  #pragma unroll
  for (int hh = 0; hh < 4; ++hh)
    #pragma unroll
    for (int jj = 0; jj < 4; ++jj) {
      size_t idx = (size_t)(B0 + j0 + jj) * HH + h0 + 64 * hh;
      u[hh][jj] = p.fu[L][idx];
      v[hh][jj] = p.fv[L][idx];
      if (p.fs[L][idx] != 0.0f) smask |= 1u << (hh * 4 + jj);
      tp[hh][jj] = 0.5f;
    }
  float bL[4];
  #pragma unroll
  for (int hh = 0; hh < 4; ++hh) bL[hh] = p.bs[L][h0 + 64 * hh];
  if (L == 2 && tid < 64) {
    size_t idx = (size_t)(B0 + (tid >> 1)) * AA + (tid & 1);
    l4u[tid] = p.f4u[idx]; l4v[tid] = p.f4v[idx]; l4s[tid] = p.f4s[idx];
    l4t[tid] = 0.5f; l4acc[tid] = 0.0f;
  }
  __syncthreads();

  // ---- one-time global init barrier (wt3 + xT visible) ----
  if (tid == 0) {
    uadd(&p.flags[260]);
    while (uload_acq(&p.flags[260]) < (unsigned)NGRID) __builtin_amdgcn_s_sleep(2);
  }
  __syncthreads();

  const float* wbase = p.wt3 + (size_t)L * WLAYER + (h0 << 2);
  float* sb_in  = (L > 0) ? p.sbuf + (size_t)(L - 1) * 2 * BB * HH : nullptr;
  float* sb_out = (L < 2) ? p.sbuf + (size_t)L * 2 * BB * HH : nullptr;

  #pragma unroll 1
  for (int t = 0; t < TT; ++t) {
    // ---- 1. stage input [k][j] into in_lds ----
    if (L == 0) {
      if (p.use_xt) {
        const float* base = p.xT + (size_t)t * (BB * SS) + (size_t)B0 * SS;
        #pragma unroll
        for (int iq = 0; iq < 4; ++iq) {
          const int j = jq * 16 + iq * 4;
          float4 vv = make_float4(base[(size_t)(j + 0) * SS + sid],
                                  base[(size_t)(j + 1) * SS + sid],
                                  base[(size_t)(j + 2) * SS + sid],
                                  base[(size_t)(j + 3) * SS + sid]);
          *reinterpret_cast<float4*>(&in_lds[sid * LSTR + j]) = vv;
        }
      } else {
        #pragma unroll
        for (int iq = 0; iq < 4; ++iq) {
          const int j = jq * 16 + iq * 4;
          float4 vv = make_float4(
              p.x[((size_t)(B0 + j + 0) * SS + sid) * TT + t],
              p.x[((size_t)(B0 + j + 1) * SS + sid) * TT + t],
              p.x[((size_t)(B0 + j + 2) * SS + sid) * TT + t],
              p.x[((size_t)(B0 + j + 3) * SS + sid) * TT + t]);
          *reinterpret_cast<float4*>(&in_lds[sid * LSTR + j]) = vv;
        }
      }
    } else {
      const int hop = L - 1;
      if (tid == 0) {
        while (uload_acq(&p.flags[hop * 64 + g]) < (unsigned)(t + 1))
          __builtin_amdgcn_s_sleep(2);
      }
      __syncthreads();
      const float* src = sb_in + (size_t)(t & 1) * BB * HH;
      #pragma unroll
      for (int iq = 0; iq < 4; ++iq) {
        const int j = jq * 16 + iq * 4;
        float4 vv = make_float4(pload(src + (size_t)(B0 + j + 0) * HH + sid),
                                pload(src + (size_t)(B0 + j + 1) * HH + sid),
                                pload(src + (size_t)(B0 + j + 2) * HH + sid),
                                pload(src + (size_t)(B0 + j + 3) * HH + sid));
        *reinterpret_cast<float4*>(&in_lds[sid * LSTR + j]) = vv;
      }
      __syncthreads();   // staging reads done
      if (tid == 0) ustore_rel(&p.flags[128 + hop * 64 + g], (unsigned)(t + 1));
    }
    __syncthreads();     // in_lds ready

    // ---- 2. GEMM: acc[hh][jj] += W[h][k]*in[k][j], ascending k (bit-exact) ----
    float acc[4][4];
    #pragma unroll
    for (int hh = 0; hh < 4; ++hh)
      #pragma unroll
      for (int jj = 0; jj < 4; ++jj) acc[hh][jj] = 0.0f;
    #pragma unroll 2
    for (int k4 = 0; k4 < 64; ++k4) {
      const float* wt = wbase + (size_t)k4 * K4PAD;
      float4 wreg[4];
      #pragma unroll
      for (int hh = 0; hh < 4; ++hh)
        wreg[hh] = *reinterpret_cast<const float4*>(wt + hh * 256);
      #pragma unroll
      for (int q = 0; q < 4; ++q) {
        const int k = k4 * 4 + q;
        float4 iv = *reinterpret_cast<const float4*>(&in_lds[k * LSTR + j0]);
        #pragma unroll
        for (int hh = 0; hh < 4; ++hh) {
          const float w = (q == 0) ? wreg[hh].x : (q == 1) ? wreg[hh].y
                        : (q == 2) ? wreg[hh].z : wreg[hh].w;
          acc[hh][0] = fmaf(iv.x, w, acc[hh][0]);
          acc[hh][1] = fmaf(iv.y, w, acc[hh][1]);
          acc[hh][2] = fmaf(iv.z, w, acc[hh][2]);
          acc[hh][3] = fmaf(iv.w, w, acc[hh][3]);
        }
      }
    }

    // ---- 3. stats(t-1): group sync, cross-block reduce, temporal update ----
    if (t > 0) {
      if (tid == 0) {
        while (uload_acq(&p.flags[256 + L]) < (unsigned)(NLG * t))
          __builtin_amdgcn_s_sleep(2);
      }
      __syncthreads();
      {
        const int wv = tid >> 6, ln = tid & 63;
        if (wv == 0 || (wv == 1 && L == 2)) {
          const int ch = (wv == 0) ? L : 3;
          const float* pb = p.partials + (size_t)(ch * 2 + ((t - 1) & 1)) * 6 * 64;
          float r[6];
          #pragma unroll
          for (int st = 0; st < 6; ++st) {
            float rr = pload(pb + st * 64 + ln);
            if (st == 0 || st == 3) {
              #pragma unroll
              for (int m = 1; m < 64; m <<= 1) rr += __shfl_xor(rr, m);
            } else if (st == 1 || st == 4) {
              #pragma unroll
              for (int m = 1; m < 64; m <<= 1) rr = fmaxf(rr, __shfl_xor(rr, m));
            } else {
              #pragma unroll
              for (int m = 1; m < 64; m <<= 1) rr = fminf(rr, __shfl_xor(rr, m));
            }
            r[st] = rr;
          }
          if (ln == 0) {
            const float invN = (ch == 3) ? (1.0f / 4096.0f) : (1.0f / 524288.0f);
            scal[wv][0] = (r[0] * invN) - 0.2f * (r[1] - r[2]);
            scal[wv][1] = (r[3] * invN) - 0.2f * (r[4] - r[5]);
          }
        }
      }
      __syncthreads();
      {
        const float Vm = scal[0][0], Vt = scal[0][1];
        #pragma unroll
        for (int hh = 0; hh < 4; ++hh)
          #pragma unroll
          for (int jj = 0; jj < 4; ++jj) {
            float d = v[hh][jj] - Vm;           // v holds v(t-1)
            float sp = logf(1.0f + expf(d * 0.25f));
            tp[hh][jj] = (0.01f * d + Vt) + sp;
          }
      }
      if (L == 2 && tid < 64) {
        const float Vm = scal[1][0], Vt = scal[1][1];
        float d = l4v[tid] - Vm;
        float sp = logf(1.0f + expf(d * 0.25f));
        l4t[tid] = (0.01f * d + Vt) + sp;
      }
      __syncthreads();
    }

    // ---- 4. LIF + per-thread/wave stats ----
    float sv = 0.f, svt = 0.f;
    float mxv = -3.402823466e38f, mnv = 3.402823466e38f;
    float mxvt = -3.402823466e38f, mnvt = 3.402823466e38f;
    unsigned nsmask = 0;
    #pragma unroll
    for (int hh = 0; hh < 4; ++hh) {
      const float bbx = bL[hh];
      #pragma unroll
      for (int jj = 0; jj < 4; ++jj) {
        float un = fmaf(u[hh][jj], 0.5f, acc[hh][jj]) + bbx;
        float vp = v[hh][jj];
        float vd = ((smask >> (hh * 4 + jj)) & 1u) ? 0.0f : vp * 0.75f;
        float vn = vd + un;
        float en = expf((vp - vn) / 3.0f) - 1.0f;
        float vt = 0.5f * tp[hh][jj] + 0.5f * en;
        const bool sx = vn > vt;
        u[hh][jj] = un; v[hh][jj] = vn;
        if (sx) nsmask |= 1u << (hh * 4 + jj);
        sv += vn; svt += vt;
        mxv = fmaxf(mxv, vn); mnv = fminf(mnv, vn);
        mxvt = fmaxf(mxvt, vt); mnvt = fminf(mnvt, vt);
      }
    }
    smask = nsmask;
    #pragma unroll
    for (int m = 1; m < 64; m <<= 1) {
      sv += __shfl_xor(sv, m);   svt += __shfl_xor(svt, m);
      mxv = fmaxf(mxv, __shfl_xor(mxv, m));  mnv = fminf(mnv, __shfl_xor(mnv, m));
      mxvt = fmaxf(mxvt, __shfl_xor(mxvt, m)); mnvt = fminf(mnvt, __shfl_xor(mnvt, m));
    }
    if ((tid & 63) == 0) {
      int wv = tid >> 6;
      wred[wv][0] = sv;  wred[wv][1] = mxv;  wred[wv][2] = mnv;
      wred[wv][3] = svt; wred[wv][4] = mxvt; wred[wv][5] = mnvt;
    }
    __syncthreads();     // wred visible

    if (L < 2) {
      // ---- 5a. partials(chL) + EARLY arrive, then publish spikes ----
      if (tid < 6) {
        const int st = tid;
        float r = wred[0][st];
        if (st == 0 || st == 3) {
          #pragma unroll
          for (int wv = 1; wv < 8; ++wv) r = r + wred[wv][st];
        } else if (st == 1 || st == 4) {
          #pragma unroll
          for (int wv = 1; wv < 8; ++wv) r = fmaxf(r, wred[wv][st]);
        } else {
          #pragma unroll
          for (int wv = 1; wv < 8; ++wv) r = fminf(r, wred[wv][st]);
        }
        pstore(p.partials + (size_t)(L * 2 + (t & 1)) * 6 * 64 + st * 64 + g, r);
      }
      if (t >= 2 && tid == 1) {       // ack poll on a different lane, overlapped
        while (uload_acq(&p.flags[128 + L * 64 + g]) < (unsigned)(t - 1))
          __builtin_amdgcn_s_sleep(2);
      }
      __syncthreads();                // partials stored + ack ok
      if (tid == 0) uadd(&p.flags[256 + L]);   // arrive stats counter EARLY
      float* dst = sb_out + (size_t)(t & 1) * BB * HH;
      #pragma unroll
      for (int hh = 0; hh < 4; ++hh)
        #pragma unroll
        for (int jj = 0; jj < 4; ++jj)
          pstore(dst + (size_t)(B0 + j0 + jj) * HH + h0 + 64 * hh,
                 ((nsmask >> (hh * 4 + jj)) & 1u) ? 1.0f : 0.0f);
      __syncthreads();                // publish stores issued by all threads
      if (tid == 0) ustore_rel(&p.flags[L * 64 + g], (unsigned)(t + 1));
    } else {
      // ---- 5b. L2: partials(ch2) + s3 spikes -> layer 4 -> ch3 -> arrive ----
      if (tid < 6) {
        const int st = tid;
        float r = wred[0][st];
        if (st == 0 || st == 3) {
          #pragma unroll
          for (int wv = 1; wv < 8; ++wv) r = r + wred[wv][st];
        } else if (st == 1 || st == 4) {
          #pragma unroll
          for (int wv = 1; wv < 8; ++wv) r = fmaxf(r, wred[wv][st]);
        } else {
          #pragma unroll
          for (int wv = 1; wv < 8; ++wv) r = fminf(r, wred[wv][st]);
        }
        pstore(p.partials + (size_t)(2 * 2 + (t & 1)) * 6 * 64 + st * 64 + g, r);
      }
      #pragma unroll
      for (int hh = 0; hh < 4; ++hh)
        #pragma unroll
        for (int jj = 0; jj < 4; ++jj)
          s3_lds[(j0 + jj) * S3P + h0 + 64 * hh] =
              ((nsmask >> (hh * 4 + jj)) & 1u) ? 1.0f : 0.0f;
      __syncthreads();   // s3 ready + ch2 partials stored

      {
        const int d = tid >> 3, c = tid & 7;   // d<64
        if (d < 64) {
          const int j4 = d >> 1, a4 = d & 1;
          float part = 0.0f;
          #pragma unroll
          for (int i = 0; i < 32; ++i) {
            int k = c + 8 * i;
            part = fmaf(s3_lds[j4 * S3P + k], p.W4[a4 * HH + k], part);
          }
          #pragma unroll
          for (int m = 1; m < 8; m <<= 1) part += __shfl_xor(part, m);
          if (c == 0) {
            float un = fmaf(l4u[d], 0.5f, part) + p.b4[a4];
            float vp = l4v[d];
            float vd = (vp * 0.75f) * (1.0f - l4s[d]);
            float vn = vd + un;
            float en = expf((vp - vn) / 3.0f) - 1.0f;
            float vt = 0.5f * l4t[d] + 0.5f * en;
            float sx = (vn > vt) ? 1.0f : 0.0f;
            l4u[d] = un; l4v[d] = vn; l4s[d] = sx;
            l4acc[d] += sx; l4vn[d] = vn; l4vth[d] = vt;
          }
        }
      }
      __syncthreads();   // l4vn/l4vth visible

      if (tid < 64) {    // parallel 64-lane reduction (replaces serial loop)
        float a = l4vn[tid], b = l4vth[tid];
        float s4 = a, mx4 = a, mn4 = a;
        float st4 = b, mxt4 = b, mnt4 = b;
        #pragma unroll
        for (int m = 1; m < 64; m <<= 1) {
          s4  += __shfl_xor(s4, m);   st4 += __shfl_xor(st4, m);
          mx4  = fmaxf(mx4,  __shfl_xor(mx4, m));  mn4  = fminf(mn4,  __shfl_xor(mn4, m));
          mxt4 = fmaxf(mxt4, __shfl_xor(mxt4, m)); mnt4 = fminf(mnt4, __shfl_xor(mnt4, m));
        }
        if (tid == 0) {
          float* pp = p.partials + (size_t)(3 * 2 + (t & 1)) * 6 * 64 + g;
          pstore(pp + 0 * 64, s4);   pstore(pp + 1 * 64, mx4);  pstore(pp + 2 * 64, mn4);
          pstore(pp + 3 * 64, st4);  pstore(pp + 4 * 64, mxt4); pstore(pp + 5 * 64, mnt4);
        }
      }
      __syncthreads();   // ch3 partials stored
      if (tid == 0) uadd(&p.flags[256 + L]);
    }
  }

  if (L == 2 && tid < 64)
    p.out[(size_t)(B0 + (tid >> 1)) * AA + (tid & 1)] = l4acc[tid] / 50.0f;
}

extern "C" void kernel_launch(void* const* d_in, const int* in_sizes, int n_in,
                              void* d_out, int out_size, void* d_ws, size_t ws_size,
                              hipStream_t stream) {
  Params p;
  p.x     = (const float*)d_in[0];
  p.fu[0] = (const float*)d_in[1];  p.fv[0] = (const float*)d_in[2];  p.fs[0] = (const float*)d_in[3];
  p.fu[1] = (const float*)d_in[4];  p.fv[1] = (const float*)d_in[5];  p.fs[1] = (const float*)d_in[6];
  p.fu[2] = (const float*)d_in[7];  p.fv[2] = (const float*)d_in[8];  p.fs[2] = (const float*)d_in[9];
  p.f4u   = (const float*)d_in[10]; p.f4v   = (const float*)d_in[11]; p.f4s   = (const float*)d_in[12];
  p.W[0]  = (const float*)d_in[13]; p.bs[0] = (const float*)d_in[14];
  p.W[1]  = (const float*)d_in[15]; p.bs[1] = (const float*)d_in[16];
  p.W[2]  = (const float*)d_in[17]; p.bs[2] = (const float*)d_in[18];
  p.W4    = (const float*)d_in[19]; p.b4    = (const float*)d_in[20];
  p.out   = (float*)d_out;

  float* ws   = (float*)d_ws;
  p.wt3       = ws;                          // 3*69632 = 208896 floats
  p.partials  = ws + 208896;                 // 4*2*6*64 = 3072
  p.flags     = (unsigned*)(ws + 211968);    // 1024 uints
  p.sbuf      = ws + 212992;                 // 2*2*2048*256 = 2,097,152
  p.xT        = ws + 2310144;                // 50*524288 = 26,214,400
  size_t need = ((size_t)2310144 + (size_t)TT * BB * SS) * sizeof(float);
  p.use_xt    = (ws_size >= need) ? 1 : 0;

  hipMemsetAsync((void*)p.flags, 0, 4096, stream);
  snn_pipe<<<dim3(NGRID), dim3(NTHR), 0, stream>>>(p);
}